// Round 10
// baseline (283.857 us; speedup 1.0000x reference)
//
#include <hip/hip_runtime.h>
#include <hip/hip_bf16.h>

// Shapes fixed by the reference: b=1, c=512, t=16, h=w=32
#define CCH   512
#define NPOS  16384
#define NTOK  1024
#define NFRM  16
#define NGRP  32
#define GSZ   (CCH / NGRP)
#define GELEM (GSZ * NPOS)
#define GN_SPLIT 32

typedef unsigned short u16;
typedef unsigned int   u32;
typedef __attribute__((ext_vector_type(8))) short  short8;
typedef __attribute__((ext_vector_type(4))) float  floatx4;

__device__ __forceinline__ float bf2f(u16 u) {
    return __uint_as_float(((u32)u) << 16);
}
__device__ __forceinline__ u16 f2bf(float f) {
    u32 u = __float_as_uint(f);
    u = (u + 0x7fffu + ((u >> 16) & 1u)) >> 16;
    return (u16)u;
}
__device__ __forceinline__ float ldx(const void* p, size_t i, bool f32m) {
    return f32m ? ((const float*)p)[i] : bf2f(((const u16*)p)[i]);
}
// async global->LDS, 16B per lane; LDS base must be wave-uniform
__device__ __forceinline__ void gl2lds16(const u16* g, u16* l) {
    __builtin_amdgcn_global_load_lds(
        (const __attribute__((address_space(1))) u32*)g,
        (__attribute__((address_space(3))) u32*)l, 16, 0, 0);
}

// per-block dtype detection from the first 16KB of x (deterministic across
// blocks -> every block computes the same answer; L2-broadcast, ~free).
__device__ __forceinline__ bool calc_f32m(const u32* __restrict__ x32) {
    __shared__ int cnt;
    if (threadIdx.x == 0) cnt = 0;
    __syncthreads();
    int c = 0;
    for (int i = threadIdx.x; i < 4096; i += 256) {
        u32 v = x32[i] & 0xFFFFu;
        u32 e = (v >> 7) & 0xFFu;
        if (e >= 0xC8u) c++;
    }
    atomicAdd(&cnt, c);
    __syncthreads();
    return cnt > 64;
}

// --------------------------------------------- fused prep: detect + convert +
// rl-zero + GroupNorm partials, ONE dispatch.
//   b in [0,1024): weight convert (4 x 512x512 -> bf16)
//   b == 1024:     bias convert (4 x 512)
//   b in [1025,1089): zero rl (64 x 256 floats)
//   b in [1089,2113): gn_partial block b-1089
// Block 0 publishes *flag for later dispatches.
__launch_bounds__(256)
__global__ void prep_all(const void* __restrict__ x,
                         const void* w0, const void* w1, const void* w2, const void* w3,
                         const void* b0, const void* b1, const void* b2, const void* b3,
                         u16* __restrict__ wdst, u16* __restrict__ bdst,
                         float* __restrict__ rl, float2* __restrict__ partials,
                         u32* __restrict__ flag) {
    int b = blockIdx.x;
    if (b >= 1025 && b < 1089) {          // zero rl
        rl[(b - 1025) * 256 + threadIdx.x] = 0.0f;
        return;
    }
    bool f32m = calc_f32m((const u32*)x);
    if (b == 0 && threadIdx.x == 0) *flag = f32m ? 1u : 0u;

    if (b < 1024) {                       // weights: 1024 elems/block
        int wi = b >> 8;
        const void* src = (wi == 0) ? w0 : (wi == 1) ? w1 : (wi == 2) ? w2 : w3;
        int base = (b & 255) * 1024 + threadIdx.x * 4;
        u16* d = wdst + wi * 262144 + base;
        if (f32m) {
            float4 v = *(const float4*)((const float*)src + base);
            ushort4 o;
            o.x = f2bf(v.x); o.y = f2bf(v.y); o.z = f2bf(v.z); o.w = f2bf(v.w);
            *(ushort4*)d = o;
        } else {
            *(ushort4*)d = *(const ushort4*)((const u16*)src + base);
        }
    } else if (b == 1024) {               // biases: 8 elems/thread
        int t = threadIdx.x;
        int bi = t >> 6;
        int off = (t & 63) * 8;
        const void* src = (bi == 0) ? b0 : (bi == 1) ? b1 : (bi == 2) ? b2 : b3;
        u16* d = bdst + bi * 512 + off;
        if (f32m) {
            float4 v1 = *(const float4*)((const float*)src + off);
            float4 v2 = *(const float4*)((const float*)src + off + 4);
            ushort4 o1, o2;
            o1.x = f2bf(v1.x); o1.y = f2bf(v1.y); o1.z = f2bf(v1.z); o1.w = f2bf(v1.w);
            o2.x = f2bf(v2.x); o2.y = f2bf(v2.y); o2.z = f2bf(v2.z); o2.w = f2bf(v2.w);
            *(ushort4*)d = o1; *(ushort4*)(d + 4) = o2;
        } else {
            *(ushort4*)d = *(const ushort4*)((const u16*)src + off);
            *(ushort4*)(d + 4) = *(const ushort4*)((const u16*)src + off + 4);
        }
    } else {                              // gn_partial, block bb = b - 1089
        __shared__ float sm[8];
        int bb = b - 1089;
        const int chunk = GELEM / GN_SPLIT;           // 8192 elements
        size_t base = (size_t)bb * chunk;
        float s = 0.f, ss = 0.f;
        if (f32m) {
            const float4* p = (const float4*)((const float*)x + base);
            for (int i = threadIdx.x; i < chunk / 4; i += 256) {
                float4 u = p[i];
                s  += u.x + u.y + u.z + u.w;
                ss += u.x * u.x + u.y * u.y + u.z * u.z + u.w * u.w;
            }
        } else {
            const ushort4* p = (const ushort4*)((const u16*)x + base);
            for (int i = threadIdx.x; i < chunk / 4; i += 256) {
                ushort4 u = p[i];
                float a = bf2f(u.x), bq = bf2f(u.y), c = bf2f(u.z), d = bf2f(u.w);
                s  += a + bq + c + d;
                ss += a * a + bq * bq + c * c + d * d;
            }
        }
        int lane = threadIdx.x & 63, w = threadIdx.x >> 6;
        float t = s;
        #pragma unroll
        for (int o = 32; o > 0; o >>= 1) t += __shfl_down(t, o, 64);
        if (lane == 0) sm[w] = t;
        t = ss;
        #pragma unroll
        for (int o = 32; o > 0; o >>= 1) t += __shfl_down(t, o, 64);
        if (lane == 0) sm[4 + w] = t;
        __syncthreads();
        if (threadIdx.x == 0)
            partials[bb] = make_float2(sm[0] + sm[1] + sm[2] + sm[3],
                                       sm[4] + sm[5] + sm[6] + sm[7]);
    }
}

// GN-apply + transpose: x [c][pos] (poly) -> xn_t [pos][c] (bf16).
// Coefs recomputed in-block; loads vectorized float4/ushort4 (G13); stores
// vectorized ushort4 (512B/wave/inst vs 128B scalar; LDS reads <=2-way=free).
__launch_bounds__(256)
__global__ void gn_apply_t(const void* __restrict__ x, const float2* __restrict__ partials,
                           const void* __restrict__ gamma, const void* __restrict__ beta,
                           u16* __restrict__ xt, const u32* __restrict__ flag) {
    bool f32m = *flag != 0u;
    __shared__ float tile[64][65];
    __shared__ float2 cfs[64];
    int p0 = blockIdx.x * 64, c0 = blockIdx.y * 64;
    if (threadIdx.x < 64) {
        int c = c0 + threadIdx.x, g = c >> 4;
        float sum = 0.f, sq = 0.f;
        #pragma unroll 8
        for (int i = 0; i < GN_SPLIT; ++i) {
            float2 p = partials[g * GN_SPLIT + i];
            sum += p.x; sq += p.y;
        }
        float mean = sum * (1.0f / (float)GELEM);
        float var  = fmaxf(sq * (1.0f / (float)GELEM) - mean * mean, 0.0f);
        float rstd = rsqrtf(var + 1e-6f);
        float gm = ldx(gamma, c, f32m), b = ldx(beta, c, f32m);
        float sc = rstd * gm;
        cfs[threadIdx.x] = make_float2(sc, b - mean * sc);
    }
    __syncthreads();
    int r16    = threadIdx.x >> 4;      // 16 rows per pass
    int lane16 = threadIdx.x & 15;      // 4 consecutive pos each
    #pragma unroll 4
    for (int pass = 0; pass < 4; ++pass) {
        int row = pass * 16 + r16;
        float2 cf = cfs[row];
        size_t base = (size_t)(c0 + row) * NPOS + p0 + lane16 * 4;
        float4 v;
        if (f32m) {
            v = *(const float4*)((const float*)x + base);
        } else {
            ushort4 u = *(const ushort4*)((const u16*)x + base);
            v = make_float4(bf2f(u.x), bf2f(u.y), bf2f(u.z), bf2f(u.w));
        }
        tile[row][lane16 * 4 + 0] = v.x * cf.x + cf.y;
        tile[row][lane16 * 4 + 1] = v.y * cf.x + cf.y;
        tile[row][lane16 * 4 + 2] = v.z * cf.x + cf.y;
        tile[row][lane16 * 4 + 3] = v.w * cf.x + cf.y;
    }
    __syncthreads();
    int c4 = (threadIdx.x & 15) * 4;    // 4 consecutive channels per thread
    #pragma unroll 4
    for (int pass = 0; pass < 4; ++pass) {
        int prow = pass * 16 + r16;
        ushort4 o;
        o.x = f2bf(tile[c4 + 0][prow]);
        o.y = f2bf(tile[c4 + 1][prow]);
        o.z = f2bf(tile[c4 + 2][prow]);
        o.w = f2bf(tile[c4 + 3][prow]);
        *(ushort4*)&xt[(size_t)(p0 + prow) * CCH + c0 + c4] = o;
    }
}

#define EPI_QK    0   // C bf16, += bias[n]
#define EPI_V     1   // C bf16, += bias[m]
#define EPI_SCEXP 2   // C bf16 = exp(v*scale); rowsum atomically into rl
#define EPI_PV    3   // C bf16 = v (UNNORMALIZED; rl-divide deferred to OUT)
#define EPI_OUT   4   // C poly, = v/rl[n] + bias[m] + resid[idx]

// --------------------------------------------------------- 128x128 TN GEMM body
// ROUND-1/4 CORE (best measured; in-block pipelining r2/r3, 8-phase r5, and
// coop fusion r9 all failed): single LDS buffer, 2 barriers/K-step, BK=64;
// stage latency hidden by OTHER resident blocks (the one proven mechanism).
// LDS swizzle (rule #21 both-sides): LDS[r][p] = G[r][p ^ (r&7)], p = 16B
// chunk 0..7; linear LDS dest (global_load_lds reqmt), pre-swizzled global
// source, same XOR on ds_read -> conflict-free (measured 0).
template<int EPI>
__device__ __forceinline__ void gemm128(
    u16* __restrict__ As, u16* __restrict__ Bs,
    const u16* __restrict__ A, const u16* __restrict__ B,
    void* __restrict__ C, const u16* __restrict__ bias,
    const void* __restrict__ resid, const u32* __restrict__ flag,
    float* __restrict__ rl, int m_blk, int n_blk, int f,
    int lda, int ldb, int ldc, int K, long aFS, long bFS, long cFS)
{
    const int tid = threadIdx.x;
    const u16* Ab = A + (size_t)f * aFS + (size_t)m_blk * 128 * lda;
    const u16* Bb = B + (size_t)f * bFS + (size_t)n_blk * 128 * ldb;

    const int wave = tid >> 6, lane = tid & 63;
    const int srow = wave * 32 + (lane >> 3);
    const int schs = ((lane & 7) ^ ((lane >> 3) & 7)) * 8;

    const int wm = (wave >> 1) * 64, wn = (wave & 1) * 64;
    const int l15 = lane & 15, quad = lane >> 4;

    floatx4 acc[4][4] = {};

    for (int kk = 0; kk < K; kk += 64) {
        __syncthreads();
        #pragma unroll
        for (int o = 0; o < 4; ++o) {
            gl2lds16(Ab + (size_t)(srow + o * 8) * lda + kk + schs, &As[wave * 2048 + o * 512]);
            gl2lds16(Bb + (size_t)(srow + o * 8) * ldb + kk + schs, &Bs[wave * 2048 + o * 512]);
        }
        __syncthreads();
        #pragma unroll
        for (int kh = 0; kh < 2; ++kh) {
            short8 af[4], bf[4];
            #pragma unroll
            for (int mi = 0; mi < 4; ++mi) {
                const int row = wm + mi * 16 + l15;
                af[mi] = *(const short8*)&As[row * 64 + (((kh << 2) | quad) ^ (row & 7)) * 8];
            }
            #pragma unroll
            for (int ni = 0; ni < 4; ++ni) {
                const int row = wn + ni * 16 + l15;
                bf[ni] = *(const short8*)&Bs[row * 64 + (((kh << 2) | quad) ^ (row & 7)) * 8];
            }
            #pragma unroll
            for (int mi = 0; mi < 4; ++mi)
                #pragma unroll
                for (int ni = 0; ni < 4; ++ni)
                    acc[mi][ni] = __builtin_amdgcn_mfma_f32_16x16x32_bf16(
                        af[mi], bf[ni], acc[mi][ni], 0, 0, 0);
        }
    }

    const bool f32m = (EPI == EPI_OUT) ? (*flag != 0u) : false;
    const int m_base = m_blk * 128 + wm;
    const int n_base = n_blk * 128 + wn;
    const float scale = 0.044194173824159216f;  // 512^-0.5

    float invn4[4];
    if (EPI == EPI_OUT) {   // deferred softmax normalization: rl indexed by n(=pos)
        #pragma unroll
        for (int ni = 0; ni < 4; ++ni)
            invn4[ni] = 1.0f / rl[n_base + ni * 16 + l15];
    }
    float rs[4][4];
    if (EPI == EPI_SCEXP) {
        #pragma unroll
        for (int mi = 0; mi < 4; ++mi)
            #pragma unroll
            for (int r = 0; r < 4; ++r) rs[mi][r] = 0.0f;
    }

    #pragma unroll
    for (int mi = 0; mi < 4; ++mi) {
        #pragma unroll
        for (int ni = 0; ni < 4; ++ni) {
            int n = n_base + ni * 16 + l15;
            float bn = (EPI == EPI_QK) ? bf2f(bias[n]) : 0.0f;
            #pragma unroll
            for (int r = 0; r < 4; ++r) {
                int m = m_base + mi * 16 + quad * 4 + r;
                float v = acc[mi][ni][r];
                size_t idx = (size_t)f * cFS + (size_t)m * ldc + n;
                if (EPI == EPI_QK) {
                    ((u16*)C)[idx] = f2bf(v + bn);
                } else if (EPI == EPI_V) {
                    ((u16*)C)[idx] = f2bf(v + bf2f(bias[m]));
                } else if (EPI == EPI_SCEXP) {
                    float ex = __expf(v * scale);
                    rs[mi][r] += ex;
                    ((u16*)C)[idx] = f2bf(ex);
                } else if (EPI == EPI_PV) {
                    ((u16*)C)[idx] = f2bf(v);
                } else {  // EPI_OUT
                    float r2 = v * invn4[ni] + bf2f(bias[m]) + ldx(resid, idx, f32m);
                    if (f32m) ((float*)C)[idx] = r2;
                    else      ((u16*)C)[idx]   = f2bf(r2);
                }
            }
        }
    }

    if (EPI == EPI_SCEXP) {
        #pragma unroll
        for (int mi = 0; mi < 4; ++mi) {
            #pragma unroll
            for (int r = 0; r < 4; ++r) {
                float s = rs[mi][r];
                s += __shfl_xor(s, 1, 64);
                s += __shfl_xor(s, 2, 64);
                s += __shfl_xor(s, 4, 64);
                s += __shfl_xor(s, 8, 64);
                if (l15 == 0)
                    atomicAdd(&rl[f * NTOK + m_base + mi * 16 + quad * 4 + r], s);
            }
        }
    }
}

// Generic 128^2 wrapper (SCEXP / PV / OUT). FSW: frame->XCD pinning.
// bound (256,4): VGPR 76 -> 4 blocks/CU resident; SCEXP grid 1024 = 4/CU
// (residency doubled vs the r8 256-tile SCEXP at 2/CU — cross-block hiding
// is the proven mechanism, more residents = more hiding).
template<int EPI, bool MX, bool FSW>
__launch_bounds__(256, 4)
__global__ void mfma_gemm(const u16* __restrict__ A, const u16* __restrict__ B,
                          void* __restrict__ C, const u16* __restrict__ bias,
                          const void* __restrict__ resid, const u32* __restrict__ flag,
                          float* __restrict__ rl,
                          int lda, int ldb, int ldc, int K,
                          long aFS, long bFS, long cFS) {
    __shared__ __align__(16) u16 As[128 * 64];
    __shared__ __align__(16) u16 Bs[128 * 64];
    int bxi, byi, f;
    if (FSW) {
        u32 id = (blockIdx.z * gridDim.y + blockIdx.y) * gridDim.x + blockIdx.x;
        u32 T = gridDim.x * gridDim.y * gridDim.z;
        u32 half = T >> 1;
        f = (int)(id & 7u) + ((id >= half) ? 8 : 0);
        u32 l = (id >= half ? id - half : id) >> 3;
        bxi = (int)(l % gridDim.x);
        byi = (int)(l / gridDim.x);
    } else {
        bxi = blockIdx.x; byi = blockIdx.y; f = blockIdx.z;
    }
    gemm128<EPI>(As, Bs, A, B, C, bias, resid, flag, rl,
                 MX ? bxi : byi, MX ? byi : bxi, f, lda, ldb, ldc, K, aFS, bFS, cFS);
}

// Merged Q/K + V projection: ONE dispatch of 1536 identical-cost 128^2 K=512
// blocks. y<8: C[pos][1024] q|k rows. y>=8: vt[cout][pos] (m_blk = y-8).
// bound (256,5): grid offers 6 blocks/CU; LDS 5x32KB = 160KB exactly fits,
// VGPR 76 < 102 cap -> 5 resident (if runtime allows only 4, no harm).
__launch_bounds__(256, 5)
__global__ void qkv_gemm(const u16* __restrict__ xnt,
                         const u16* __restrict__ wqk, const u16* __restrict__ bqk,
                         u16* __restrict__ qkt,
                         const u16* __restrict__ wv, const u16* __restrict__ bv,
                         u16* __restrict__ vt,
                         const u32* __restrict__ flag) {
    __shared__ __align__(16) u16 As[128 * 64];
    __shared__ __align__(16) u16 Bs[128 * 64];
    if (blockIdx.y < 8) {
        gemm128<EPI_QK>(As, Bs, xnt, wqk, qkt, bqk, nullptr, flag, nullptr,
                        (int)blockIdx.x, (int)blockIdx.y, 0,
                        CCH, CCH, 1024, CCH, 0, 0, 0);
    } else {
        gemm128<EPI_V>(As, Bs, wv, xnt, vt, bv, nullptr, flag, nullptr,
                       (int)blockIdx.y - 8, (int)blockIdx.x, 0,
                       CCH, CCH, NPOS, CCH, 0, 0, 0);
    }
}

// ---------------------------------------------------------------- launcher
extern "C" void kernel_launch(void* const* d_in, const int* in_sizes, int n_in,
                              void* d_out, int out_size, void* d_ws, size_t ws_size,
                              hipStream_t stream) {
    const void* x   = d_in[0];
    const void* gam = d_in[1];
    const void* bet = d_in[2];

    // Workspace (100 MiB):
    //   [4K,+8K) partials  [12352) flag
    //   [16K,+2Mi) bf16 weights (contig)  [~2.1Mi,+4K) bf16 biases (contig)
    //   [3Mi) rl (16384 f32)
    //   [4Mi) xnt 16Mi (reused as obuf)  [20Mi) qkt 32Mi (q cols 0..511, k cols 512..1023)
    //   [52Mi) vt 16Mi
    //   [68Mi) P bf16 16x1024x1024 = 32Mi
    char* ws = (char*)d_ws;
    float2* partials = (float2*)(ws + 4096);
    u32*    flag     = (u32*)(ws + 12352);
    u16* cw[4] = { (u16*)(ws + 16384),              (u16*)(ws + 16384 +  524288ull),
                   (u16*)(ws + 16384 + 1048576ull), (u16*)(ws + 16384 + 1572864ull) };
    u16* cb[4] = { (u16*)(ws + 2113536ull),        (u16*)(ws + 2113536ull + 1024),
                   (u16*)(ws + 2113536ull + 2048), (u16*)(ws + 2113536ull + 3072) };
    float* rl  = (float*)(ws + (3ull << 20));
    u16*  xnt  = (u16*)(ws + (4ull  << 20));
    u16*  qkt  = (u16*)(ws + (20ull << 20));
    u16*  vt   = (u16*)(ws + (52ull << 20));
    u16*  pbuf = (u16*)(ws + (68ull << 20));
    u16*  obuf = xnt;

    // fused detect + weight/bias convert + rl zero + GN partials (one dispatch)
    prep_all<<<2113, 256, 0, stream>>>(x,
                                       d_in[3], d_in[5], d_in[7], d_in[9],
                                       d_in[4], d_in[6], d_in[8], d_in[10],
                                       cw[0], cb[0], rl, partials, flag);
    // GN apply + transpose (vectorized loads AND stores)
    gn_apply_t<<<dim3(NPOS / 64, CCH / 64), 256, 0, stream>>>(
        x, partials, gam, bet, xnt, flag);

    // merged q/k + v projections: one dispatch, 1536 identical-cost blocks
    qkv_gemm<<<dim3(128, 12), 256, 0, stream>>>(
        xnt, cw[0], cb[0], qkt, cw[2], cb[2], vt, flag);

    // scores + exp + rowsum: 128^2 tiles, grid 1024 = 4 resident/CU
    dim3 gsc(NTOK / 128, NTOK / 128, NFRM);   // (8, 8, 16), frame->XCD pinned
    mfma_gemm<EPI_SCEXP, false, true><<<gsc, 256, 0, stream>>>(
        qkt, qkt + 512, pbuf, nullptr, nullptr, flag, rl, 1024, 1024, NTOK, CCH,
        (long)NTOK * 1024, (long)NTOK * 1024, (long)NTOK * NTOK);

    // PV (unnormalized): obuf[i][c] = P_i . V_c   (rl-divide deferred to OUT)
    dim3 gpv(CCH / 128, NTOK / 128, NFRM);    // (4, 8, 16), frame->XCD pinned
    mfma_gemm<EPI_PV, false, true><<<gpv, 256, 0, stream>>>(
        pbuf, vt, obuf, nullptr, nullptr, flag, nullptr, NTOK, NPOS, CCH, NTOK,
        (long)NTOK * NTOK, NTOK, (long)NTOK * CCH);

    // out: C[cout][pos] = (Wo . O)/rl[pos] + bo + x, poly store
    dim3 go(NPOS / 128, CCH / 128, 1);    // (128, 4)
    mfma_gemm<EPI_OUT, false, false><<<go, 256, 0, stream>>>(
        cw[3], obuf, d_out, cb[3], x, flag, rl, CCH, CCH, NPOS, CCH, 0, 0, 0);
}

// Round 11
// 219.266 us; speedup vs baseline: 1.2946x; 1.2946x over previous
//
#include <hip/hip_runtime.h>
#include <hip/hip_bf16.h>

// Shapes fixed by the reference: b=1, c=512, t=16, h=w=32
#define CCH   512
#define NPOS  16384
#define NTOK  1024
#define NFRM  16
#define NGRP  32
#define GSZ   (CCH / NGRP)
#define GELEM (GSZ * NPOS)
#define GN_SPLIT 32

typedef unsigned short u16;
typedef unsigned int   u32;
typedef __attribute__((ext_vector_type(8))) short  short8;
typedef __attribute__((ext_vector_type(4))) float  floatx4;

__device__ __forceinline__ float bf2f(u16 u) {
    return __uint_as_float(((u32)u) << 16);
}
__device__ __forceinline__ u16 f2bf(float f) {
    u32 u = __float_as_uint(f);
    u = (u + 0x7fffu + ((u >> 16) & 1u)) >> 16;
    return (u16)u;
}
__device__ __forceinline__ float ldx(const void* p, size_t i, bool f32m) {
    return f32m ? ((const float*)p)[i] : bf2f(((const u16*)p)[i]);
}
// async global->LDS, 16B per lane; LDS base must be wave-uniform
__device__ __forceinline__ void gl2lds16(const u16* g, u16* l) {
    __builtin_amdgcn_global_load_lds(
        (const __attribute__((address_space(1))) u32*)g,
        (__attribute__((address_space(3))) u32*)l, 16, 0, 0);
}

// per-block dtype detection from the first 16KB of x (deterministic across
// blocks -> every block computes the same answer; L2-broadcast, ~free).
__device__ __forceinline__ bool calc_f32m(const u32* __restrict__ x32) {
    __shared__ int cnt;
    if (threadIdx.x == 0) cnt = 0;
    __syncthreads();
    int c = 0;
    for (int i = threadIdx.x; i < 4096; i += 256) {
        u32 v = x32[i] & 0xFFFFu;
        u32 e = (v >> 7) & 0xFFu;
        if (e >= 0xC8u) c++;
    }
    atomicAdd(&cnt, c);
    __syncthreads();
    return cnt > 64;
}

// --------------------------------------------- fused prep: detect + convert +
// rl-zero + GroupNorm partials, ONE dispatch.
//   b in [0,1024): weight convert (4 x 512x512 -> bf16)
//   b == 1024:     bias convert (4 x 512)
//   b in [1025,1089): zero rl (64 x 256 floats)
//   b in [1089,2113): gn_partial block b-1089
// Block 0 publishes *flag for later dispatches.
__launch_bounds__(256)
__global__ void prep_all(const void* __restrict__ x,
                         const void* w0, const void* w1, const void* w2, const void* w3,
                         const void* b0, const void* b1, const void* b2, const void* b3,
                         u16* __restrict__ wdst, u16* __restrict__ bdst,
                         float* __restrict__ rl, float2* __restrict__ partials,
                         u32* __restrict__ flag) {
    int b = blockIdx.x;
    if (b >= 1025 && b < 1089) {          // zero rl
        rl[(b - 1025) * 256 + threadIdx.x] = 0.0f;
        return;
    }
    bool f32m = calc_f32m((const u32*)x);
    if (b == 0 && threadIdx.x == 0) *flag = f32m ? 1u : 0u;

    if (b < 1024) {                       // weights: 1024 elems/block
        int wi = b >> 8;
        const void* src = (wi == 0) ? w0 : (wi == 1) ? w1 : (wi == 2) ? w2 : w3;
        int base = (b & 255) * 1024 + threadIdx.x * 4;
        u16* d = wdst + wi * 262144 + base;
        if (f32m) {
            float4 v = *(const float4*)((const float*)src + base);
            ushort4 o;
            o.x = f2bf(v.x); o.y = f2bf(v.y); o.z = f2bf(v.z); o.w = f2bf(v.w);
            *(ushort4*)d = o;
        } else {
            *(ushort4*)d = *(const ushort4*)((const u16*)src + base);
        }
    } else if (b == 1024) {               // biases: 8 elems/thread
        int t = threadIdx.x;
        int bi = t >> 6;
        int off = (t & 63) * 8;
        const void* src = (bi == 0) ? b0 : (bi == 1) ? b1 : (bi == 2) ? b2 : b3;
        u16* d = bdst + bi * 512 + off;
        if (f32m) {
            float4 v1 = *(const float4*)((const float*)src + off);
            float4 v2 = *(const float4*)((const float*)src + off + 4);
            ushort4 o1, o2;
            o1.x = f2bf(v1.x); o1.y = f2bf(v1.y); o1.z = f2bf(v1.z); o1.w = f2bf(v1.w);
            o2.x = f2bf(v2.x); o2.y = f2bf(v2.y); o2.z = f2bf(v2.z); o2.w = f2bf(v2.w);
            *(ushort4*)d = o1; *(ushort4*)(d + 4) = o2;
        } else {
            *(ushort4*)d = *(const ushort4*)((const u16*)src + off);
            *(ushort4*)(d + 4) = *(const ushort4*)((const u16*)src + off + 4);
        }
    } else {                              // gn_partial, block bb = b - 1089
        __shared__ float sm[8];
        int bb = b - 1089;
        const int chunk = GELEM / GN_SPLIT;           // 8192 elements
        size_t base = (size_t)bb * chunk;
        float s = 0.f, ss = 0.f;
        if (f32m) {
            const float4* p = (const float4*)((const float*)x + base);
            for (int i = threadIdx.x; i < chunk / 4; i += 256) {
                float4 u = p[i];
                s  += u.x + u.y + u.z + u.w;
                ss += u.x * u.x + u.y * u.y + u.z * u.z + u.w * u.w;
            }
        } else {
            const ushort4* p = (const ushort4*)((const u16*)x + base);
            for (int i = threadIdx.x; i < chunk / 4; i += 256) {
                ushort4 u = p[i];
                float a = bf2f(u.x), bq = bf2f(u.y), c = bf2f(u.z), d = bf2f(u.w);
                s  += a + bq + c + d;
                ss += a * a + bq * bq + c * c + d * d;
            }
        }
        int lane = threadIdx.x & 63, w = threadIdx.x >> 6;
        float t = s;
        #pragma unroll
        for (int o = 32; o > 0; o >>= 1) t += __shfl_down(t, o, 64);
        if (lane == 0) sm[w] = t;
        t = ss;
        #pragma unroll
        for (int o = 32; o > 0; o >>= 1) t += __shfl_down(t, o, 64);
        if (lane == 0) sm[4 + w] = t;
        __syncthreads();
        if (threadIdx.x == 0)
            partials[bb] = make_float2(sm[0] + sm[1] + sm[2] + sm[3],
                                       sm[4] + sm[5] + sm[6] + sm[7]);
    }
}

// GN-apply + transpose: x [c][pos] (poly) -> xn_t [pos][c] (bf16).
// Per-channel affine coefficients recomputed IN-BLOCK from group partials.
// Loads VECTORIZED (G13): float4/ushort4, 4 pos per thread per pass.
__launch_bounds__(256)
__global__ void gn_apply_t(const void* __restrict__ x, const float2* __restrict__ partials,
                           const void* __restrict__ gamma, const void* __restrict__ beta,
                           u16* __restrict__ xt, const u32* __restrict__ flag) {
    bool f32m = *flag != 0u;
    __shared__ float tile[64][65];
    __shared__ float2 cfs[64];
    int p0 = blockIdx.x * 64, c0 = blockIdx.y * 64;
    if (threadIdx.x < 64) {
        int c = c0 + threadIdx.x, g = c >> 4;
        float sum = 0.f, sq = 0.f;
        #pragma unroll 8
        for (int i = 0; i < GN_SPLIT; ++i) {
            float2 p = partials[g * GN_SPLIT + i];
            sum += p.x; sq += p.y;
        }
        float mean = sum * (1.0f / (float)GELEM);
        float var  = fmaxf(sq * (1.0f / (float)GELEM) - mean * mean, 0.0f);
        float rstd = rsqrtf(var + 1e-6f);
        float gm = ldx(gamma, c, f32m), b = ldx(beta, c, f32m);
        float sc = rstd * gm;
        cfs[threadIdx.x] = make_float2(sc, b - mean * sc);
    }
    __syncthreads();
    int r16    = threadIdx.x >> 4;      // 16 rows per pass
    int lane16 = threadIdx.x & 15;      // 4 consecutive pos each
    #pragma unroll 4
    for (int pass = 0; pass < 4; ++pass) {
        int row = pass * 16 + r16;
        float2 cf = cfs[row];
        size_t base = (size_t)(c0 + row) * NPOS + p0 + lane16 * 4;
        float4 v;
        if (f32m) {
            v = *(const float4*)((const float*)x + base);
        } else {
            ushort4 u = *(const ushort4*)((const u16*)x + base);
            v = make_float4(bf2f(u.x), bf2f(u.y), bf2f(u.z), bf2f(u.w));
        }
        tile[row][lane16 * 4 + 0] = v.x * cf.x + cf.y;
        tile[row][lane16 * 4 + 1] = v.y * cf.x + cf.y;
        tile[row][lane16 * 4 + 2] = v.z * cf.x + cf.y;
        tile[row][lane16 * 4 + 3] = v.w * cf.x + cf.y;
    }
    __syncthreads();
    int lane = threadIdx.x & 63, rg = threadIdx.x >> 6;
    #pragma unroll 4
    for (int i = 0; i < 16; ++i) {
        int prow = rg * 16 + i;
        xt[(size_t)(p0 + prow) * CCH + c0 + lane] = f2bf(tile[lane][prow]);
    }
}

#define EPI_QK    0   // C bf16, += bias[n]
#define EPI_V     1   // C bf16, += bias[m]
#define EPI_SCEXP 2   // C bf16 = exp(v*scale); rowsum atomically into rl
#define EPI_PV    3   // C bf16 = v (UNNORMALIZED; rl-divide deferred to OUT)
#define EPI_OUT   4   // C poly, = v/rl[n] + bias[m] + resid[idx]

// --------------------------------------------------------- 128x128 TN GEMM body
// ROUND-1/4 CORE (best measured): single LDS buffer, 2 barriers/K-step, BK=64;
// stage latency hidden by OTHER resident blocks. LDS swizzle (rule #21
// both-sides): LDS[r][p] = G[r][p ^ (r&7)], p = 16B chunk 0..7; linear LDS
// dest (global_load_lds reqmt), pre-swizzled global source, same XOR on
// ds_read -> conflict-free (measured 0).
// NOTE (r10 lesson): do NOT raise launch_bounds past 4 blocks/CU — (256,5)
// re-ran regalloc to 48 VGPR with scratch spills (FETCH 26->74 MB, 2.2x slower).
template<int EPI>
__device__ __forceinline__ void gemm128(
    u16* __restrict__ As, u16* __restrict__ Bs,
    const u16* __restrict__ A, const u16* __restrict__ B,
    void* __restrict__ C, const u16* __restrict__ bias,
    const void* __restrict__ resid, const u32* __restrict__ flag,
    float* __restrict__ rl, int m_blk, int n_blk, int f,
    int lda, int ldb, int ldc, int K, long aFS, long bFS, long cFS)
{
    const int tid = threadIdx.x;
    const u16* Ab = A + (size_t)f * aFS + (size_t)m_blk * 128 * lda;
    const u16* Bb = B + (size_t)f * bFS + (size_t)n_blk * 128 * ldb;

    const int wave = tid >> 6, lane = tid & 63;
    const int srow = wave * 32 + (lane >> 3);
    const int schs = ((lane & 7) ^ ((lane >> 3) & 7)) * 8;

    const int wm = (wave >> 1) * 64, wn = (wave & 1) * 64;
    const int l15 = lane & 15, quad = lane >> 4;

    floatx4 acc[4][4] = {};

    for (int kk = 0; kk < K; kk += 64) {
        __syncthreads();
        #pragma unroll
        for (int o = 0; o < 4; ++o) {
            gl2lds16(Ab + (size_t)(srow + o * 8) * lda + kk + schs, &As[wave * 2048 + o * 512]);
            gl2lds16(Bb + (size_t)(srow + o * 8) * ldb + kk + schs, &Bs[wave * 2048 + o * 512]);
        }
        __syncthreads();
        #pragma unroll
        for (int kh = 0; kh < 2; ++kh) {
            short8 af[4], bf[4];
            #pragma unroll
            for (int mi = 0; mi < 4; ++mi) {
                const int row = wm + mi * 16 + l15;
                af[mi] = *(const short8*)&As[row * 64 + (((kh << 2) | quad) ^ (row & 7)) * 8];
            }
            #pragma unroll
            for (int ni = 0; ni < 4; ++ni) {
                const int row = wn + ni * 16 + l15;
                bf[ni] = *(const short8*)&Bs[row * 64 + (((kh << 2) | quad) ^ (row & 7)) * 8];
            }
            #pragma unroll
            for (int mi = 0; mi < 4; ++mi)
                #pragma unroll
                for (int ni = 0; ni < 4; ++ni)
                    acc[mi][ni] = __builtin_amdgcn_mfma_f32_16x16x32_bf16(
                        af[mi], bf[ni], acc[mi][ni], 0, 0, 0);
        }
    }

    const bool f32m = (EPI == EPI_OUT) ? (*flag != 0u) : false;
    const int m_base = m_blk * 128 + wm;
    const int n_base = n_blk * 128 + wn;
    const float scale = 0.044194173824159216f;  // 512^-0.5

    float invn4[4];
    if (EPI == EPI_OUT) {   // deferred softmax normalization: rl indexed by n(=pos)
        #pragma unroll
        for (int ni = 0; ni < 4; ++ni)
            invn4[ni] = 1.0f / rl[n_base + ni * 16 + l15];
    }
    float rs[4][4];
    if (EPI == EPI_SCEXP) {
        #pragma unroll
        for (int mi = 0; mi < 4; ++mi)
            #pragma unroll
            for (int r = 0; r < 4; ++r) rs[mi][r] = 0.0f;
    }

    #pragma unroll
    for (int mi = 0; mi < 4; ++mi) {
        #pragma unroll
        for (int ni = 0; ni < 4; ++ni) {
            int n = n_base + ni * 16 + l15;
            float bn = (EPI == EPI_QK) ? bf2f(bias[n]) : 0.0f;
            #pragma unroll
            for (int r = 0; r < 4; ++r) {
                int m = m_base + mi * 16 + quad * 4 + r;
                float v = acc[mi][ni][r];
                size_t idx = (size_t)f * cFS + (size_t)m * ldc + n;
                if (EPI == EPI_QK) {
                    ((u16*)C)[idx] = f2bf(v + bn);
                } else if (EPI == EPI_V) {
                    ((u16*)C)[idx] = f2bf(v + bf2f(bias[m]));
                } else if (EPI == EPI_SCEXP) {
                    float ex = __expf(v * scale);
                    rs[mi][r] += ex;
                    ((u16*)C)[idx] = f2bf(ex);
                } else if (EPI == EPI_PV) {
                    ((u16*)C)[idx] = f2bf(v);
                } else {  // EPI_OUT
                    float r2 = v * invn4[ni] + bf2f(bias[m]) + ldx(resid, idx, f32m);
                    if (f32m) ((float*)C)[idx] = r2;
                    else      ((u16*)C)[idx]   = f2bf(r2);
                }
            }
        }
    }

    if (EPI == EPI_SCEXP) {
        #pragma unroll
        for (int mi = 0; mi < 4; ++mi) {
            #pragma unroll
            for (int r = 0; r < 4; ++r) {
                float s = rs[mi][r];
                s += __shfl_xor(s, 1, 64);
                s += __shfl_xor(s, 2, 64);
                s += __shfl_xor(s, 4, 64);
                s += __shfl_xor(s, 8, 64);
                if (l15 == 0)
                    atomicAdd(&rl[f * NTOK + m_base + mi * 16 + quad * 4 + r], s);
            }
        }
    }
}

// Generic 128^2 wrapper (PV / OUT). FSW: frame->XCD pinning for z-batched GEMMs.
// bound (256,4): VGPR_Count=76 measured -> 4 blocks/CU, no spills.
template<int EPI, bool MX, bool FSW>
__launch_bounds__(256, 4)
__global__ void mfma_gemm(const u16* __restrict__ A, const u16* __restrict__ B,
                          void* __restrict__ C, const u16* __restrict__ bias,
                          const void* __restrict__ resid, const u32* __restrict__ flag,
                          float* __restrict__ rl,
                          int lda, int ldb, int ldc, int K,
                          long aFS, long bFS, long cFS) {
    __shared__ __align__(16) u16 As[128 * 64];
    __shared__ __align__(16) u16 Bs[128 * 64];
    int bxi, byi, f;
    if (FSW) {
        u32 id = (blockIdx.z * gridDim.y + blockIdx.y) * gridDim.x + blockIdx.x;
        u32 T = gridDim.x * gridDim.y * gridDim.z;
        u32 half = T >> 1;
        f = (int)(id & 7u) + ((id >= half) ? 8 : 0);
        u32 l = (id >= half ? id - half : id) >> 3;
        bxi = (int)(l % gridDim.x);
        byi = (int)(l / gridDim.x);
    } else {
        bxi = blockIdx.x; byi = blockIdx.y; f = blockIdx.z;
    }
    gemm128<EPI>(As, Bs, A, B, C, bias, resid, flag, rl,
                 MX ? bxi : byi, MX ? byi : bxi, f, lda, ldb, ldc, K, aFS, bFS, cFS);
}

// Merged Q/K + V projection: ONE dispatch of 1536 identical-cost 128^2 K=512
// blocks. y<8: C[pos][1024] q|k rows. y>=8: vt[cout][pos] (m_blk = y-8).
// bound (256,4): 4 resident/CU, VGPR 76, no spills (r10: (256,5) spilled).
__launch_bounds__(256, 4)
__global__ void qkv_gemm(const u16* __restrict__ xnt,
                         const u16* __restrict__ wqk, const u16* __restrict__ bqk,
                         u16* __restrict__ qkt,
                         const u16* __restrict__ wv, const u16* __restrict__ bv,
                         u16* __restrict__ vt,
                         const u32* __restrict__ flag) {
    __shared__ __align__(16) u16 As[128 * 64];
    __shared__ __align__(16) u16 Bs[128 * 64];
    if (blockIdx.y < 8) {
        gemm128<EPI_QK>(As, Bs, xnt, wqk, qkt, bqk, nullptr, flag, nullptr,
                        (int)blockIdx.x, (int)blockIdx.y, 0,
                        CCH, CCH, 1024, CCH, 0, 0, 0);
    } else {
        gemm128<EPI_V>(As, Bs, wv, xnt, vt, bv, nullptr, flag, nullptr,
                       (int)blockIdx.y - 8, (int)blockIdx.x, 0,
                       CCH, CCH, NPOS, CCH, 0, 0, 0);
    }
}

// --------------------------------------------------------- 256x128 TN GEMM
// r4's BM=256 variant (512 thr, 8 waves 4m x 2n): +33% MFMA/staged-byte,
// half the block count. Used for SCEXP (grid (8,4,16) = 512 blocks, 2/CU).
// r10 confirmed: this beats 128^2@4-resident for SCEXP (~17 us).
template<int EPI, bool FSW>
__launch_bounds__(512, 4)
__global__ void mfma_gemm256(const u16* __restrict__ A, const u16* __restrict__ B,
                             void* __restrict__ C, const u16* __restrict__ bias,
                             const u32* __restrict__ flag, float* __restrict__ rl,
                             int lda, int ldb, int ldc, int K,
                             long aFS, long bFS, long cFS) {
    __shared__ __align__(16) u16 As[256 * 64];   // 32 KB
    __shared__ __align__(16) u16 Bs[128 * 64];   // 16 KB
    const int tid = threadIdx.x;

    int bxi, byi, f;
    if (FSW) {
        u32 id = (blockIdx.z * gridDim.y + blockIdx.y) * gridDim.x + blockIdx.x;
        u32 T = gridDim.x * gridDim.y * gridDim.z;
        u32 half = T >> 1;
        f = (int)(id & 7u) + ((id >= half) ? 8 : 0);
        u32 l = (id >= half ? id - half : id) >> 3;
        bxi = (int)(l % gridDim.x);
        byi = (int)(l / gridDim.x);
    } else {
        bxi = blockIdx.x; byi = blockIdx.y; f = blockIdx.z;
    }
    const int m_blk = byi;
    const int n_blk = bxi;

    const u16* Ab = A + (size_t)f * aFS + (size_t)m_blk * 256 * lda;
    const u16* Bb = B + (size_t)f * bFS + (size_t)n_blk * 128 * ldb;

    const int wave = tid >> 6, lane = tid & 63;
    const int srowA = wave * 32 + (lane >> 3);
    const int srowB = wave * 16 + (lane >> 3);
    const int schs  = ((lane & 7) ^ ((lane >> 3) & 7)) * 8;

    const int wm = (wave >> 1) * 64, wn = (wave & 1) * 64;
    const int l15 = lane & 15, quad = lane >> 4;

    floatx4 acc[4][4] = {};

    for (int kk = 0; kk < K; kk += 64) {
        __syncthreads();
        #pragma unroll
        for (int o = 0; o < 4; ++o)
            gl2lds16(Ab + (size_t)(srowA + o * 8) * lda + kk + schs,
                     &As[wave * 2048 + o * 512]);
        #pragma unroll
        for (int o = 0; o < 2; ++o)
            gl2lds16(Bb + (size_t)(srowB + o * 8) * ldb + kk + schs,
                     &Bs[wave * 1024 + o * 512]);
        __syncthreads();
        #pragma unroll
        for (int kh = 0; kh < 2; ++kh) {
            short8 af[4], bf[4];
            #pragma unroll
            for (int mi = 0; mi < 4; ++mi) {
                const int row = wm + mi * 16 + l15;
                af[mi] = *(const short8*)&As[row * 64 + (((kh << 2) | quad) ^ (row & 7)) * 8];
            }
            #pragma unroll
            for (int ni = 0; ni < 4; ++ni) {
                const int row = wn + ni * 16 + l15;
                bf[ni] = *(const short8*)&Bs[row * 64 + (((kh << 2) | quad) ^ (row & 7)) * 8];
            }
            #pragma unroll
            for (int mi = 0; mi < 4; ++mi)
                #pragma unroll
                for (int ni = 0; ni < 4; ++ni)
                    acc[mi][ni] = __builtin_amdgcn_mfma_f32_16x16x32_bf16(
                        af[mi], bf[ni], acc[mi][ni], 0, 0, 0);
        }
    }

    const int m_base = m_blk * 256 + wm;
    const int n_base = n_blk * 128 + wn;
    const float scale = 0.044194173824159216f;  // 512^-0.5

    float rs[4][4];
    #pragma unroll
    for (int mi = 0; mi < 4; ++mi)
        #pragma unroll
        for (int r = 0; r < 4; ++r) rs[mi][r] = 0.0f;

    #pragma unroll
    for (int mi = 0; mi < 4; ++mi) {
        #pragma unroll
        for (int ni = 0; ni < 4; ++ni) {
            int n = n_base + ni * 16 + l15;
            #pragma unroll
            for (int r = 0; r < 4; ++r) {
                int m = m_base + mi * 16 + quad * 4 + r;
                float v = acc[mi][ni][r];
                size_t idx = (size_t)f * cFS + (size_t)m * ldc + n;
                float ex = __expf(v * scale);       // EPI_SCEXP only
                rs[mi][r] += ex;
                ((u16*)C)[idx] = f2bf(ex);
            }
        }
    }

    #pragma unroll
    for (int mi = 0; mi < 4; ++mi) {
        #pragma unroll
        for (int r = 0; r < 4; ++r) {
            float s = rs[mi][r];
            s += __shfl_xor(s, 1, 64);
            s += __shfl_xor(s, 2, 64);
            s += __shfl_xor(s, 4, 64);
            s += __shfl_xor(s, 8, 64);
            if (l15 == 0)
                atomicAdd(&rl[f * NTOK + m_base + mi * 16 + quad * 4 + r], s);
        }
    }
}

// ---------------------------------------------------------------- launcher
extern "C" void kernel_launch(void* const* d_in, const int* in_sizes, int n_in,
                              void* d_out, int out_size, void* d_ws, size_t ws_size,
                              hipStream_t stream) {
    const void* x   = d_in[0];
    const void* gam = d_in[1];
    const void* bet = d_in[2];

    // Workspace (100 MiB):
    //   [4K,+8K) partials  [12352) flag
    //   [16K,+2Mi) bf16 weights (contig)  [~2.1Mi,+4K) bf16 biases (contig)
    //   [3Mi) rl (16384 f32)
    //   [4Mi) xnt 16Mi (reused as obuf)  [20Mi) qkt 32Mi (q cols 0..511, k cols 512..1023)
    //   [52Mi) vt 16Mi
    //   [68Mi) P bf16 16x1024x1024 = 32Mi
    char* ws = (char*)d_ws;
    float2* partials = (float2*)(ws + 4096);
    u32*    flag     = (u32*)(ws + 12352);
    u16* cw[4] = { (u16*)(ws + 16384),              (u16*)(ws + 16384 +  524288ull),
                   (u16*)(ws + 16384 + 1048576ull), (u16*)(ws + 16384 + 1572864ull) };
    u16* cb[4] = { (u16*)(ws + 2113536ull),        (u16*)(ws + 2113536ull + 1024),
                   (u16*)(ws + 2113536ull + 2048), (u16*)(ws + 2113536ull + 3072) };
    float* rl  = (float*)(ws + (3ull << 20));
    u16*  xnt  = (u16*)(ws + (4ull  << 20));
    u16*  qkt  = (u16*)(ws + (20ull << 20));
    u16*  vt   = (u16*)(ws + (52ull << 20));
    u16*  pbuf = (u16*)(ws + (68ull << 20));
    u16*  obuf = xnt;

    // fused detect + weight/bias convert + rl zero + GN partials (one dispatch)
    prep_all<<<2113, 256, 0, stream>>>(x,
                                       d_in[3], d_in[5], d_in[7], d_in[9],
                                       d_in[4], d_in[6], d_in[8], d_in[10],
                                       cw[0], cb[0], rl, partials, flag);
    // GN apply + transpose (coef recomputed in-block; vectorized loads)
    gn_apply_t<<<dim3(NPOS / 64, CCH / 64), 256, 0, stream>>>(
        x, partials, gam, bet, xnt, flag);

    // merged q/k + v projections: one dispatch, 1536 identical-cost blocks
    qkv_gemm<<<dim3(128, 12), 256, 0, stream>>>(
        xnt, cw[0], cb[0], qkt, cw[2], cb[2], vt, flag);

    // scores + exp + rowsum: P[f][i][j] = exp(scale*q_i.k_j), rl[f*1024+i] += rowsum
    dim3 gsc(NTOK / 128, NTOK / 256, NFRM);   // (8, 4, 16), frame->XCD pinned
    mfma_gemm256<EPI_SCEXP, true><<<gsc, 512, 0, stream>>>(
        qkt, qkt + 512, pbuf, nullptr, flag, rl, 1024, 1024, NTOK, CCH,
        (long)NTOK * 1024, (long)NTOK * 1024, (long)NTOK * NTOK);

    // PV (unnormalized): obuf[i][c] = P_i . V_c   (rl-divide deferred to OUT)
    dim3 gpv(CCH / 128, NTOK / 128, NFRM);    // (4, 8, 16), frame->XCD pinned
    mfma_gemm<EPI_PV, false, true><<<gpv, 256, 0, stream>>>(
        pbuf, vt, obuf, nullptr, nullptr, flag, nullptr, NTOK, NPOS, CCH, NTOK,
        (long)NTOK * NTOK, NTOK, (long)NTOK * CCH);

    // out: C[cout][pos] = (Wo . O)/rl[pos] + bo + x, poly store
    dim3 go(NPOS / 128, CCH / 128, 1);    // (128, 4)
    mfma_gemm<EPI_OUT, false, false><<<go, 256, 0, stream>>>(
        cw[3], obuf, d_out, cb[3], x, flag, rl, CCH, CCH, NPOS, CCH, 0, 0, 0);
}